// Round 9
// baseline (472.969 us; speedup 1.0000x reference)
//
#include <hip/hip_runtime.h>
#include <math.h>

// Problem constants
#define HW 65536          // 256*256
#define NPAD 258          // padded spatial dim

typedef short bf16x8 __attribute__((ext_vector_type(8)));
typedef float f32x4  __attribute__((ext_vector_type(4)));

// Workspace layout (bytes)
#define O_COUNTS 0            // 12 * 32 ints = 1536 B
#define O_W2C    2048         // 8 * 16 floats = 512 B
#define O_WT     4096         // 2 convs * 36864 bf16 = 147456 B  [cv][h][tap][q][co][8ci]
#define O_META   151552       // 12 * 65536 ints = 3 MiB
#define O_FUSED  3297280      // 8*258*258*64 bf16 = 68,161,536 B
#define O_X1     71458816     // same size

// Conv LDS: half-channel tile: 6 rows x 66 px x 64 B (32 ci). Two buffers.
#define HROWB   4224              // 66 px * 64 B
#define HROWSTR 4240
#define HBUF    25440             // 6 * HROWSTR, one buffer

#define SCHED0()  __builtin_amdgcn_sched_barrier(0)

__device__ __forceinline__ unsigned short f2bf(float f) {
    unsigned int u = __float_as_uint(f);
    u += 0x7FFFu + ((u >> 16) & 1u);   // round-to-nearest-even
    return (unsigned short)(u >> 16);
}

// Pack two f32 -> two bf16 in one u32 (RNE), single instruction.
__device__ __forceinline__ unsigned int cvt_pk_bf16(float lo, float hi) {
    unsigned int r;
    asm("v_cvt_pk_bf16_f32 %0, %1, %2" : "=v"(r) : "v"(lo), "v"(hi));
    return r;
}

// Fast erf-based GELU (Abramowitz-Stegun 7.1.26, |err_erf| <= 1.5e-7).
__device__ __forceinline__ float gelu_fast(float v) {
    float x  = v * 0.70710678118654752f;
    float ax = fabsf(x);
    float t  = __builtin_amdgcn_rcpf(fmaf(0.3275911f, ax, 1.0f));
    float p  = fmaf(t, 1.061405429f, -1.453152027f);
    p = fmaf(t, p, 1.421413741f);
    p = fmaf(t, p, -0.284496736f);
    p = fmaf(t, p, 0.254829592f);
    p = p * t;
    float e   = __expf(-x * x);
    float era = fmaf(-p, e, 1.0f);
    float er  = copysignf(era, x);
    return 0.5f * v * (1.0f + er);
}

// ---------------------------------------------------------------------------
// Prep: invert extrinsics, build bf16 weight fragment image [h][tap][q][co][8ci],
// zero padded-buffer borders, zero counts
// ---------------------------------------------------------------------------
__global__ __launch_bounds__(256) void prep_kernel(
    const float* __restrict__ extr, const float* __restrict__ w1,
    const float* __restrict__ w2, float* __restrict__ w2c,
    unsigned short* __restrict__ wT, unsigned short* __restrict__ fusedP,
    unsigned short* __restrict__ x1P, int* __restrict__ counts)
{
    int tid = blockIdx.x * blockDim.x + threadIdx.x;
    int nth = gridDim.x * blockDim.x;

    if (blockIdx.x == 0) {
        if (threadIdx.x < 8) {
            float a[4][8];
            const float* E = extr + threadIdx.x * 16;
            for (int r = 0; r < 4; r++)
                for (int c = 0; c < 4; c++) {
                    a[r][c] = E[r*4 + c];
                    a[r][4+c] = (r == c) ? 1.0f : 0.0f;
                }
            for (int col = 0; col < 4; col++) {
                int piv = col; float bm = fabsf(a[col][col]);
                for (int r = col+1; r < 4; r++) {
                    float v = fabsf(a[r][col]);
                    if (v > bm) { bm = v; piv = r; }
                }
                if (piv != col)
                    for (int c = 0; c < 8; c++) { float t = a[col][c]; a[col][c] = a[piv][c]; a[piv][c] = t; }
                float f = 1.0f / a[col][col];
                for (int c = 0; c < 8; c++) a[col][c] *= f;
                for (int r = 0; r < 4; r++) if (r != col) {
                    float f2 = a[r][col];
                    for (int c = 0; c < 8; c++) a[r][c] -= f2 * a[col][c];
                }
            }
            float* O = w2c + threadIdx.x * 16;
            for (int r = 0; r < 4; r++)
                for (int c = 0; c < 4; c++) O[r*4+c] = a[r][4+c];
        }
    }

    // Zero padded count slots (12 * 32 ints)
    for (int i = tid; i < 384; i += nth) counts[i] = 0;

    // Weight fragment image: 2 convs * [h2][tap9][q4][co64][j8]
    for (int e = tid; e < 73728; e += nth) {
        int t = e;
        int j  = t & 7;  t >>= 3;
        int co = t & 63; t >>= 6;
        int q  = t & 3;  t >>= 2;
        int tap = t % 9; t /= 9;
        int h  = t & 1;  int cv = t >> 1;
        int ci = h*32 + q*8 + j;
        int ky = tap / 3, kx = tap % 3;
        const float* wsrc = cv ? w2 : w1;
        float v = wsrc[((co*64 + ci)*3 + ky)*3 + kx];
        wT[cv*36864 + ((((h*9 + tap)*4 + q)*64 + co)*8 + j)] = f2bf(v);
    }

    // Zero borders of both padded buffers
    for (int u = tid; u < 2*8*1028*8; u += nth) {
        int t = u;
        int ch   = t & 7;    t >>= 3;
        int cell = t % 1028; t /= 1028;
        int n    = t & 7;    int buf = t >> 3;
        int y, x;
        if      (cell < 258) { y = 0;   x = cell; }
        else if (cell < 516) { y = 257; x = cell - 258; }
        else if (cell < 772) { y = cell - 516 + 1; x = 0; }
        else                 { y = cell - 772 + 1; x = 257; }
        unsigned short* p = (buf ? x1P : fusedP) +
            (((size_t)(n*NPAD + y)*NPAD + x)*64 + ch*8);
        *reinterpret_cast<uint4*>(p) = make_uint4(0u, 0u, 0u, 0u);
    }
}

// ---------------------------------------------------------------------------
// Projection: per (b, j->k) pair, compute mask|idx per point + valid counts.
// ---------------------------------------------------------------------------
__global__ __launch_bounds__(256) void proj_kernel(
    const float* __restrict__ means, const float* __restrict__ intr,
    const float* __restrict__ w2c, int* __restrict__ meta,
    int* __restrict__ counts)
{
    const int jt[6] = {0,1,1,2,2,3};
    const int kt[6] = {1,0,2,1,3,2};
    int s = blockIdx.y;            // 0..11
    int b = s / 6, p = s % 6;
    int j = jt[p], k = kt[p];
    int i = blockIdx.x * 256 + threadIdx.x;

    __shared__ int bcnt;
    if (threadIdx.x == 0) bcnt = 0;
    __syncthreads();

    const float* mp = means + ((size_t)(b*4 + j)*HW + i)*3;
    float x = mp[0], y = mp[1], z = mp[2];
    const float* M = w2c + (b*4 + k)*16;
    const float* I = intr + (b*4 + k)*9;

    float cx = fmaf(M[2],  z, fmaf(M[1], y, M[0]*x)) + M[3];
    float cy = fmaf(M[6],  z, fmaf(M[5], y, M[4]*x)) + M[7];
    float cz = fmaf(M[10], z, fmaf(M[9], y, M[8]*x)) + M[11];

    bool vz = cz > 1e-8f;
    float zi = cz + 1e-8f;
    float sx = cx / zi, sy = cy / zi, sz = cz / zi;
    float nx = fmaf(I[2], sz, fmaf(I[1], sy, I[0]*sx));
    float ny = fmaf(I[5], sz, fmaf(I[4], sy, I[3]*sx));

    int px = (int)floorf(nx * 256.0f);
    int py = (int)floorf(ny * 256.0f);
    bool mask = (nx >= 0.0f) && (nx < 1.0f) && (ny >= 0.0f) && (ny < 1.0f) && vz;
    int pxc = min(max(px, 0), 255);
    int pyc = min(max(py, 0), 255);
    int idx = pyc*256 + pxc;
    meta[(size_t)s*HW + i] = idx | (mask ? (int)0x80000000 : 0);

    unsigned long long bal = __ballot(mask ? 1 : 0);
    if ((threadIdx.x & 63) == 0)
        atomicAdd(&bcnt, (int)__popcll(bal));
    __syncthreads();
    if (threadIdx.x == 0)
        atomicAdd(counts + s*32, bcnt);
}

// ---------------------------------------------------------------------------
// Fusion: acc = feats_j + sum_k scale_k * masked_gather(feats_k); /norm; bf16
// ---------------------------------------------------------------------------
__global__ __launch_bounds__(256) void fuse_kernel(
    const float* __restrict__ feats, const int* __restrict__ meta,
    const int* __restrict__ counts, unsigned short* __restrict__ fusedP)
{
    const int nsl[4]    = {1, 2, 2, 1};
    const int slt[4][2] = {{0,0},{1,2},{3,4},{5,5}};
    const int kvw[4][2] = {{1,1},{0,2},{1,3},{2,2}};

    int bj = blockIdx.y;           // n = b*4 + j
    int b = bj >> 2, j = bj & 3;
    int pt = blockIdx.x * 16 + (threadIdx.x >> 4);
    int cg = threadIdx.x & 15;

    const float4* fj = reinterpret_cast<const float4*>(
        feats + ((size_t)bj*HW + pt)*64) + cg;
    float4 acc = *fj;
    float norm = 1.0f;
    int ns = nsl[j];
    for (int e = 0; e < 2; e++) {
        if (e < ns) {
            int p = slt[j][e], k = kvw[j][e];
            int s = b*6 + p;
            float scale = 0.1f * (float)counts[s*32] / 65536.0f;
            int mt = meta[(size_t)s*HW + pt];
            if (mt < 0) {
                int idx = mt & 0xFFFF;
                const float4* g = reinterpret_cast<const float4*>(
                    feats + ((size_t)(b*4 + k)*HW + idx)*64) + cg;
                float4 gv = *g;
                acc.x += scale * gv.x; acc.y += scale * gv.y;
                acc.z += scale * gv.z; acc.w += scale * gv.w;
            }
            norm += scale;
        }
    }
    float rn = 1.0f / norm;

    int yy = pt >> 8, xx = pt & 255;
    unsigned short* op = fusedP +
        (((size_t)bj*NPAD + (yy+1))*NPAD + (xx+1))*64 + cg*4;
    uint2 o = make_uint2(cvt_pk_bf16(acc.x*rn, acc.y*rn),
                         cvt_pk_bf16(acc.z*rn, acc.w*rn));
    *reinterpret_cast<uint2*>(op) = o;
}

// ---------------------------------------------------------------------------
// 3x3 conv, 2-tile pipelined, REG-STAGED (T14): identical to the round-6
// structure except the staging mechanism: global_load_dwordx4 -> VGPR ->
// ds_write_b128 replaces global_load_lds. This isolates the hypothesis that
// the LDS-DMA path's shallow outstanding-op queue is the invariant ~75 µs
// bottleneck (all pipes <25% busy across 9 structural variants; AITER/HK
// both reg-stage their bulk staging). Loads for step s+1 issue BEFORE
// COMPUTE(s) (SCHED0-pinned), ds_writes after (register-true dependency,
// compiler inserts the vmcnt wait). With per-lane LDS scatter now possible,
// global loads are LINEAR; the XOR swizzle moves to the ds_write address
// (write-side XOR == read-side XOR, both-sides rule).
//
// Swizzle: LDS slot (px, c of 16B) holds chunk c ^ ((px>>1)&3); ds_write
// lane formula (lane>>2)*64 + (((lane&3)^((lane>>3)&3))<<4) per 1 KB unit —
// full-coverage unique slots -> conflict-free b128 writes. ds_read side
// unchanged from r6. MFMA operands swapped (weights=A, pixels=B). Weight
// loads wave-uniform-base + voffset + imm (saddr). No min-waves pin (r3).
// Wave w stages rows {w, w+4(<6)}: waves 0,1 hold 10 uint4 (40 VGPR), all
// indices compile-time (rule #20).
// ---------------------------------------------------------------------------
template<int MODE>
__global__ __launch_bounds__(256) void conv_kernel(
    const unsigned short* __restrict__ in, const unsigned short* __restrict__ wT,
    const float* __restrict__ bias, void* __restrict__ outp)
{
    __shared__ unsigned short smem[2 * HBUF / 2];   // 50880 B = two buffers

    // XCD-bijective remap: image = fid&7; tile pair = rows y0 and y0+128.
    int fid = blockIdx.x;          // 0..1023
    int n   = fid & 7;             // image 0..7
    int rem = fid >> 3;            // 0..127
    int y0  = (rem >> 2) << 2;     // 0..124
    int X0  = (rem & 3) << 6;      // 0,64,128,192

    int w  = threadIdx.x >> 6;     // wave id: output row y0+w
    int lane = threadIdx.x & 63;
    int m = lane & 15, q = lane >> 4;

    // Reg-staging per-lane offsets.
    // Global (linear, no swizzle): main unit i covers px i*16+(lane>>2),
    // chunk lane&3 -> byte i*2048 + (lane>>2)*128 + (lane&3)*16.
    int gsrc  = ((lane >> 2) * 128) + ((lane & 3) << 4);
    // Tail px 64,65 (lanes 0..7): byte 8192 + (lane>>2)*128 + (lane&3)*16.
    int gtail = 8192 + gsrc;
    // LDS write (swizzled): unit i -> i*1024 + (lane>>2)*64 + (c^s(px))*16.
    int wls = ((lane >> 2) * 64) + ((((lane & 3) ^ ((lane >> 3) & 3)) & 3) << 4);

    // ds_read per-lane bases (one per dx; q fixed per lane so XOR collapses).
    int vb[3];
#pragma unroll
    for (int dx = 0; dx < 3; dx++)
        vb[dx] = w*HROWSTR + m*64 + (((q ^ (((m + dx) >> 1) & 3)) & 3) << 4);

    int wvoff = q*1024 + m*16;     // per-lane weight fragment offset (bytes)

    const char* gb00 = (const char*)in +
        (((size_t)(n*NPAD) + y0) * NPAD + X0) * 128;

    // Staged registers: wave w rows {w, w+4 if <6}. 5 units per row.
    uint4 rg[10];

    // Issue global loads for half-channel h of tile at row offset row128.
    auto LOADR = [&](int row128, int h) {
        const char* gb = gb00 + (size_t)row128 * (NPAD*128) + h*64;
        {
            const char* g = gb + (size_t)w * (NPAD*128);
#pragma unroll
            for (int i = 0; i < 4; i++)
                rg[i] = *reinterpret_cast<const uint4*>(g + i*2048 + gsrc);
            if (lane < 8)
                rg[4] = *reinterpret_cast<const uint4*>(g + gtail);
        }
        if (w < 2) {
            const char* g = gb + (size_t)(w + 4) * (NPAD*128);
#pragma unroll
            for (int i = 0; i < 4; i++)
                rg[5+i] = *reinterpret_cast<const uint4*>(g + i*2048 + gsrc);
            if (lane < 8)
                rg[9] = *reinterpret_cast<const uint4*>(g + gtail);
        }
    };

    // Write staged registers into buffer buf (swizzled LDS scatter).
    auto WRITER = [&](int buf) {
        char* lb = (char*)smem + buf*HBUF;
        {
            char* l = lb + w*HROWSTR;
#pragma unroll
            for (int i = 0; i < 4; i++)
                *reinterpret_cast<uint4*>(l + i*1024 + wls) = rg[i];
            if (lane < 8)
                *reinterpret_cast<uint4*>(l + 4096 + lane*16) = rg[4];
        }
        if (w < 2) {
            char* l = lb + (w + 4)*HROWSTR;
#pragma unroll
            for (int i = 0; i < 4; i++)
                *reinterpret_cast<uint4*>(l + i*1024 + wls) = rg[5+i];
            if (lane < 8)
                *reinterpret_cast<uint4*>(l + 4096 + lane*16) = rg[9];
        }
    };

    f32x4 acc[4][4];
    auto ACCZERO = [&]() {
#pragma unroll
        for (int a = 0; a < 4; a++)
#pragma unroll
            for (int bq = 0; bq < 4; bq++)
                acc[a][bq] = (f32x4){0.f, 0.f, 0.f, 0.f};
    };

    // 9 taps of half-channel h from buffer buf (K=32 -> 1 MFMA per (Mt,Nt))
    auto COMPUTE = [&](int h, int buf) {
        const char* sb = (const char*)smem + buf*HBUF;
        const char* wbase = (const char*)wT + h*36864;   // wave-uniform
        __builtin_amdgcn_s_setprio(1);
#pragma unroll
        for (int tap = 0; tap < 9; tap++) {
            int dy = tap/3, dx = tap%3;
            const char* wtap = wbase + tap*4096;
            bf16x8 av[4], bv[4];
#pragma unroll
            for (int Mt = 0; Mt < 4; Mt++)
                av[Mt] = *reinterpret_cast<const bf16x8*>(
                    sb + vb[dx] + dy*HROWSTR + Mt*1024 + dx*64);
#pragma unroll
            for (int Nt = 0; Nt < 4; Nt++)
                bv[Nt] = *reinterpret_cast<const bf16x8*>(wtap + wvoff + Nt*256);
#pragma unroll
            for (int Mt = 0; Mt < 4; Mt++)
#pragma unroll
                for (int Nt = 0; Nt < 4; Nt++)
                    acc[Mt][Nt] = __builtin_amdgcn_mfma_f32_16x16x32_bf16(
                        bv[Nt], av[Mt], acc[Mt][Nt], 0, 0, 0);
        }
        __builtin_amdgcn_s_setprio(0);
    };

    // Epilogue for tile at row offset row128.
    auto EPI = [&](int row128) {
        int yout = y0 + row128 + w;
        float4 bsv[4];
#pragma unroll
        for (int Nt = 0; Nt < 4; Nt++)
            bsv[Nt] = *reinterpret_cast<const float4*>(bias + Nt*16 + q*4);
        if (MODE == 1) {
            char* obase = (char*)outp +
                (((size_t)(n*NPAD + yout + 1))*NPAD + (X0 + 1))*128 + m*128 + q*8;
#pragma unroll
            for (int Mt = 0; Mt < 4; Mt++) {
                char* ob = obase + Mt*2048;
#pragma unroll
                for (int Nt = 0; Nt < 4; Nt++) {
                    float v0 = gelu_fast(acc[Mt][Nt][0] + bsv[Nt].x);
                    float v1 = gelu_fast(acc[Mt][Nt][1] + bsv[Nt].y);
                    float v2 = gelu_fast(acc[Mt][Nt][2] + bsv[Nt].z);
                    float v3 = gelu_fast(acc[Mt][Nt][3] + bsv[Nt].w);
                    uint2 pk = make_uint2(cvt_pk_bf16(v0, v1), cvt_pk_bf16(v2, v3));
                    *reinterpret_cast<uint2*>(ob + Nt*32) = pk;
                }
            }
        } else {
            char* obase = (char*)outp +
                (((size_t)(n*256 + yout))*256 + X0)*256 + m*256 + q*16;
#pragma unroll
            for (int Mt = 0; Mt < 4; Mt++) {
                char* ob = obase + Mt*4096;
#pragma unroll
                for (int Nt = 0; Nt < 4; Nt++) {
                    float4 v = make_float4(acc[Mt][Nt][0] + bsv[Nt].x,
                                           acc[Mt][Nt][1] + bsv[Nt].y,
                                           acc[Mt][Nt][2] + bsv[Nt].z,
                                           acc[Mt][Nt][3] + bsv[Nt].w);
                    *reinterpret_cast<float4*>(ob + Nt*64) = v;
                }
            }
        }
    };

    // ---- 4-step pipeline: (t0,h0) (t0,h1) (t1,h0) (t1,h1) ----
    // WAR audit: WRITER(bX) in step s targets the buffer whose last reader
    // was COMPUTE in step s-1, fenced by step s-1's __syncthreads. Readers
    // of the written buffer start after step s's __syncthreads (drains lgkm).
    ACCZERO();
    LOADR(0, 0);
    WRITER(0);                     // compiler waits vmcnt per-reg
    __syncthreads();               // prologue: b0 ready

    LOADR(0, 1); SCHED0();         // issue (t0,h1) loads before compute
    COMPUTE(0, 0);
    WRITER(1);                     // (t0,h1) -> b1 (vmcnt wait covered)
    __syncthreads();

    LOADR(128, 0); SCHED0();       // issue (t1,h0)
    COMPUTE(1, 1);                 // tile0 acc complete
    WRITER(0);
    EPI(0);
    ACCZERO();
    __syncthreads();

    LOADR(128, 1); SCHED0();       // issue (t1,h1)
    COMPUTE(0, 0);
    WRITER(1);
    __syncthreads();

    COMPUTE(1, 1);
    EPI(128);
}

extern "C" void kernel_launch(void* const* d_in, const int* in_sizes, int n_in,
                              void* d_out, int out_size, void* d_ws, size_t ws_size,
                              hipStream_t stream)
{
    const float* means = (const float*)d_in[0];
    const float* feats = (const float*)d_in[2];
    const float* intr  = (const float*)d_in[3];
    const float* extr  = (const float*)d_in[4];
    const float* w1    = (const float*)d_in[5];
    const float* b1    = (const float*)d_in[6];
    const float* w2    = (const float*)d_in[7];
    const float* b2    = (const float*)d_in[8];

    char* ws = (char*)d_ws;
    int*            counts = (int*)(ws + O_COUNTS);
    float*          w2c    = (float*)(ws + O_W2C);
    unsigned short* wT     = (unsigned short*)(ws + O_WT);
    int*            meta   = (int*)(ws + O_META);
    unsigned short* fusedP = (unsigned short*)(ws + O_FUSED);
    unsigned short* x1P    = (unsigned short*)(ws + O_X1);

    prep_kernel<<<dim3(96), dim3(256), 0, stream>>>(
        extr, w1, w2, w2c, wT, fusedP, x1P, counts);
    proj_kernel<<<dim3(256, 12), dim3(256), 0, stream>>>(
        means, intr, w2c, meta, counts);
    fuse_kernel<<<dim3(4096, 8), dim3(256), 0, stream>>>(
        feats, meta, counts, fusedP);
    conv_kernel<1><<<dim3(1024), dim3(256), 0, stream>>>(
        fusedP, wT, b1, (void*)x1P);
    conv_kernel<2><<<dim3(1024), dim3(256), 0, stream>>>(
        x1P, wT + 36864, b2, d_out);
}

// Round 10
// 380.601 us; speedup vs baseline: 1.2427x; 1.2427x over previous
//
#include <hip/hip_runtime.h>
#include <math.h>

// Problem constants
#define HW 65536          // 256*256
#define NPAD 258          // padded spatial dim

typedef short bf16x8 __attribute__((ext_vector_type(8)));
typedef float f32x4  __attribute__((ext_vector_type(4)));

// Workspace layout (bytes)
#define O_COUNTS 0            // 12 * 32 ints = 1536 B
#define O_W2C    2048         // 8 * 16 floats = 512 B
#define O_WT     4096         // 2 convs * 36864 bf16 = 147456 B  [cv][h][tap][q][co][8ci]
#define O_META   151552       // 12 * 65536 ints = 3 MiB
#define O_FUSED  3297280      // 8*258*258*64 bf16 = 68,161,536 B
#define O_X1     71458816     // same size

// Conv LDS: half-channel tile: 6 rows x 66 px x 64 B (32 ci). Two buffers.
#define HROWB   4224              // 66 px * 64 B
#define HROWSTR 4240
#define HBUF    25440             // 6 * HROWSTR, one buffer

__device__ __forceinline__ unsigned short f2bf(float f) {
    unsigned int u = __float_as_uint(f);
    u += 0x7FFFu + ((u >> 16) & 1u);   // round-to-nearest-even
    return (unsigned short)(u >> 16);
}

// Pack two f32 -> two bf16 in one u32 (RNE), single instruction.
__device__ __forceinline__ unsigned int cvt_pk_bf16(float lo, float hi) {
    unsigned int r;
    asm("v_cvt_pk_bf16_f32 %0, %1, %2" : "=v"(r) : "v"(lo), "v"(hi));
    return r;
}

// Fast erf-based GELU (Abramowitz-Stegun 7.1.26, |err_erf| <= 1.5e-7).
__device__ __forceinline__ float gelu_fast(float v) {
    float x  = v * 0.70710678118654752f;
    float ax = fabsf(x);
    float t  = __builtin_amdgcn_rcpf(fmaf(0.3275911f, ax, 1.0f));
    float p  = fmaf(t, 1.061405429f, -1.453152027f);
    p = fmaf(t, p, 1.421413741f);
    p = fmaf(t, p, -0.284496736f);
    p = fmaf(t, p, 0.254829592f);
    p = p * t;
    float e   = __expf(-x * x);
    float era = fmaf(-p, e, 1.0f);
    float er  = copysignf(era, x);
    return 0.5f * v * (1.0f + er);
}

// ---------------------------------------------------------------------------
// Prep: invert extrinsics, build bf16 weight fragment image [h][tap][q][co][8ci],
// zero padded-buffer borders, zero counts
// ---------------------------------------------------------------------------
__global__ __launch_bounds__(256) void prep_kernel(
    const float* __restrict__ extr, const float* __restrict__ w1,
    const float* __restrict__ w2, float* __restrict__ w2c,
    unsigned short* __restrict__ wT, unsigned short* __restrict__ fusedP,
    unsigned short* __restrict__ x1P, int* __restrict__ counts)
{
    int tid = blockIdx.x * blockDim.x + threadIdx.x;
    int nth = gridDim.x * blockDim.x;

    if (blockIdx.x == 0) {
        if (threadIdx.x < 8) {
            float a[4][8];
            const float* E = extr + threadIdx.x * 16;
            for (int r = 0; r < 4; r++)
                for (int c = 0; c < 4; c++) {
                    a[r][c] = E[r*4 + c];
                    a[r][4+c] = (r == c) ? 1.0f : 0.0f;
                }
            for (int col = 0; col < 4; col++) {
                int piv = col; float bm = fabsf(a[col][col]);
                for (int r = col+1; r < 4; r++) {
                    float v = fabsf(a[r][col]);
                    if (v > bm) { bm = v; piv = r; }
                }
                if (piv != col)
                    for (int c = 0; c < 8; c++) { float t = a[col][c]; a[col][c] = a[piv][c]; a[piv][c] = t; }
                float f = 1.0f / a[col][col];
                for (int c = 0; c < 8; c++) a[col][c] *= f;
                for (int r = 0; r < 4; r++) if (r != col) {
                    float f2 = a[r][col];
                    for (int c = 0; c < 8; c++) a[r][c] -= f2 * a[col][c];
                }
            }
            float* O = w2c + threadIdx.x * 16;
            for (int r = 0; r < 4; r++)
                for (int c = 0; c < 4; c++) O[r*4+c] = a[r][4+c];
        }
    }

    // Zero padded count slots (12 * 32 ints)
    for (int i = tid; i < 384; i += nth) counts[i] = 0;

    // Weight fragment image: 2 convs * [h2][tap9][q4][co64][j8]
    for (int e = tid; e < 73728; e += nth) {
        int t = e;
        int j  = t & 7;  t >>= 3;
        int co = t & 63; t >>= 6;
        int q  = t & 3;  t >>= 2;
        int tap = t % 9; t /= 9;
        int h  = t & 1;  int cv = t >> 1;
        int ci = h*32 + q*8 + j;
        int ky = tap / 3, kx = tap % 3;
        const float* wsrc = cv ? w2 : w1;
        float v = wsrc[((co*64 + ci)*3 + ky)*3 + kx];
        wT[cv*36864 + ((((h*9 + tap)*4 + q)*64 + co)*8 + j)] = f2bf(v);
    }

    // Zero borders of both padded buffers
    for (int u = tid; u < 2*8*1028*8; u += nth) {
        int t = u;
        int ch   = t & 7;    t >>= 3;
        int cell = t % 1028; t /= 1028;
        int n    = t & 7;    int buf = t >> 3;
        int y, x;
        if      (cell < 258) { y = 0;   x = cell; }
        else if (cell < 516) { y = 257; x = cell - 258; }
        else if (cell < 772) { y = cell - 516 + 1; x = 0; }
        else                 { y = cell - 772 + 1; x = 257; }
        unsigned short* p = (buf ? x1P : fusedP) +
            (((size_t)(n*NPAD + y)*NPAD + x)*64 + ch*8);
        *reinterpret_cast<uint4*>(p) = make_uint4(0u, 0u, 0u, 0u);
    }
}

// ---------------------------------------------------------------------------
// Projection: per (b, j->k) pair, compute mask|idx per point + valid counts.
// ---------------------------------------------------------------------------
__global__ __launch_bounds__(256) void proj_kernel(
    const float* __restrict__ means, const float* __restrict__ intr,
    const float* __restrict__ w2c, int* __restrict__ meta,
    int* __restrict__ counts)
{
    const int jt[6] = {0,1,1,2,2,3};
    const int kt[6] = {1,0,2,1,3,2};
    int s = blockIdx.y;            // 0..11
    int b = s / 6, p = s % 6;
    int j = jt[p], k = kt[p];
    int i = blockIdx.x * 256 + threadIdx.x;

    __shared__ int bcnt;
    if (threadIdx.x == 0) bcnt = 0;
    __syncthreads();

    const float* mp = means + ((size_t)(b*4 + j)*HW + i)*3;
    float x = mp[0], y = mp[1], z = mp[2];
    const float* M = w2c + (b*4 + k)*16;
    const float* I = intr + (b*4 + k)*9;

    float cx = fmaf(M[2],  z, fmaf(M[1], y, M[0]*x)) + M[3];
    float cy = fmaf(M[6],  z, fmaf(M[5], y, M[4]*x)) + M[7];
    float cz = fmaf(M[10], z, fmaf(M[9], y, M[8]*x)) + M[11];

    bool vz = cz > 1e-8f;
    float zi = cz + 1e-8f;
    float sx = cx / zi, sy = cy / zi, sz = cz / zi;
    float nx = fmaf(I[2], sz, fmaf(I[1], sy, I[0]*sx));
    float ny = fmaf(I[5], sz, fmaf(I[4], sy, I[3]*sx));

    int px = (int)floorf(nx * 256.0f);
    int py = (int)floorf(ny * 256.0f);
    bool mask = (nx >= 0.0f) && (nx < 1.0f) && (ny >= 0.0f) && (ny < 1.0f) && vz;
    int pxc = min(max(px, 0), 255);
    int pyc = min(max(py, 0), 255);
    int idx = pyc*256 + pxc;
    meta[(size_t)s*HW + i] = idx | (mask ? (int)0x80000000 : 0);

    unsigned long long bal = __ballot(mask ? 1 : 0);
    if ((threadIdx.x & 63) == 0)
        atomicAdd(&bcnt, (int)__popcll(bal));
    __syncthreads();
    if (threadIdx.x == 0)
        atomicAdd(counts + s*32, bcnt);
}

// ---------------------------------------------------------------------------
// Fusion: acc = feats_j + sum_k scale_k * masked_gather(feats_k); /norm; bf16
// ---------------------------------------------------------------------------
__global__ __launch_bounds__(256) void fuse_kernel(
    const float* __restrict__ feats, const int* __restrict__ meta,
    const int* __restrict__ counts, unsigned short* __restrict__ fusedP)
{
    const int nsl[4]    = {1, 2, 2, 1};
    const int slt[4][2] = {{0,0},{1,2},{3,4},{5,5}};
    const int kvw[4][2] = {{1,1},{0,2},{1,3},{2,2}};

    int bj = blockIdx.y;           // n = b*4 + j
    int b = bj >> 2, j = bj & 3;
    int pt = blockIdx.x * 16 + (threadIdx.x >> 4);
    int cg = threadIdx.x & 15;

    const float4* fj = reinterpret_cast<const float4*>(
        feats + ((size_t)bj*HW + pt)*64) + cg;
    float4 acc = *fj;
    float norm = 1.0f;
    int ns = nsl[j];
    for (int e = 0; e < 2; e++) {
        if (e < ns) {
            int p = slt[j][e], k = kvw[j][e];
            int s = b*6 + p;
            float scale = 0.1f * (float)counts[s*32] / 65536.0f;
            int mt = meta[(size_t)s*HW + pt];
            if (mt < 0) {
                int idx = mt & 0xFFFF;
                const float4* g = reinterpret_cast<const float4*>(
                    feats + ((size_t)(b*4 + k)*HW + idx)*64) + cg;
                float4 gv = *g;
                acc.x += scale * gv.x; acc.y += scale * gv.y;
                acc.z += scale * gv.z; acc.w += scale * gv.w;
            }
            norm += scale;
        }
    }
    float rn = 1.0f / norm;

    int yy = pt >> 8, xx = pt & 255;
    unsigned short* op = fusedP +
        (((size_t)bj*NPAD + (yy+1))*NPAD + (xx+1))*64 + cg*4;
    uint2 o = make_uint2(cvt_pk_bf16(acc.x*rn, acc.y*rn),
                         cvt_pk_bf16(acc.z*rn, acc.w*rn));
    *reinterpret_cast<uint2*>(op) = o;
}

// ---------------------------------------------------------------------------
// 3x3 conv, 2-tile pipelined (r6 structure — best measured) + CONVOY DESYNC.
//
// Why desync: across 10 structural variants (staging DMA vs reg, occupancy
// 8-16 waves/CU, pipeline depth 0-2, counted vmcnt, swizzle, VALU/address
// minimization) conv is flat at ~73-90 µs while MFMA-busy ~15 µs, VALU ~5,
// HBM ~20: all pipes idle most of the time. Co-resident blocks start
// together and run an IDENTICAL stage/barrier/compute rhythm -> their stall
// windows coincide and TLP cannot interleave block A's compute with block
// B's stage-wait. Fix: skew each block's start by ((fid>>8)&3) * ~2880 cyc
// (co-resident blocks at this grid differ in fid by ~256), one ~phase apart.
// Cost if theory wrong: <= 1.5 us one-time skew.
//
// Rest identical to round 6: tiles t0 (rows y0..y0+3) and t1 (y0+128..) of
// one image (XCD map: image = fid&7), 4 half-channel steps over two 25.4 KB
// LDS buffers, each step prefetching the next half-tile via global_load_lds
// (16B, pre-swizzled global source; LDS slot (px,c) holds chunk c^((px>>1)&3)).
// MFMA operands swapped (weights=A, pixels=B) -> 4 contiguous co per lane ->
// vectorized stores. Weight loads saddr-form. No min-waves pin (r3 lesson:
// VGPR forced to 40, acc spilled, 3.5x slower). Reg-staging is WORSE (r9:
// +50 us — VGPR 132 crossed the 128 occupancy step AND added 60 MB traffic).
// ---------------------------------------------------------------------------
template<int MODE>
__global__ __launch_bounds__(256) void conv_kernel(
    const unsigned short* __restrict__ in, const unsigned short* __restrict__ wT,
    const float* __restrict__ bias, void* __restrict__ outp)
{
    __shared__ unsigned short smem[2 * HBUF / 2];   // 50880 B = two buffers

    // XCD-bijective remap: image = fid&7; tile pair = rows y0 and y0+128.
    int fid = blockIdx.x;          // 0..1023
    int n   = fid & 7;             // image 0..7
    int rem = fid >> 3;            // 0..127
    int y0  = (rem >> 2) << 2;     // 0..124
    int X0  = (rem & 3) << 6;      // 0,64,128,192

    // Convoy desync: blocks co-resident on a CU differ in fid by ~256 at
    // this grid; stagger their pipelines by ~one step-phase each.
    {
        int skew = (fid >> 8) & 3;
        for (int i = 0; i < skew * 3; i++) __builtin_amdgcn_s_sleep(15);
    }

    int w  = threadIdx.x >> 6;     // wave id: output row y0+w
    int lane = threadIdx.x & 63;
    int m = lane & 15, q = lane >> 4;

    // Staging per-lane source offsets (relative to a (row, h) strip base).
    int srcl = ((lane >> 2) * 128) + ((((lane & 3) ^ ((lane >> 3) & 3)) & 3) << 4);
    int tsrcl = 8192 + ((lane >> 2) * 128) + ((lane & 3) << 4);

    // ds_read per-lane bases (one per dx; q fixed per lane so XOR collapses).
    int vb[3];
#pragma unroll
    for (int dx = 0; dx < 3; dx++)
        vb[dx] = w*HROWSTR + m*64 + (((q ^ (((m + dx) >> 1) & 3)) & 3) << 4);

    int wvoff = q*1024 + m*16;     // per-lane weight fragment offset (bytes)

    const char* gb00 = (const char*)in +
        (((size_t)(n*NPAD) + y0) * NPAD + X0) * 128;

    // Stage half-channel h of tile at row offset row128 into buffer buf.
    auto STAGE = [&](int row128, int h, int buf) {
        const char* gb = gb00 + (size_t)row128 * (NPAD*128) + h*64;
        char* lb = (char*)smem + buf*HBUF;
        for (int ri = w; ri < 6; ri += 4) {
            const char* g = gb + (size_t)ri * (NPAD*128);
            char* l = lb + ri*HROWSTR;
#pragma unroll
            for (int i = 0; i < 4; i++)
                __builtin_amdgcn_global_load_lds(
                    (const __attribute__((address_space(1))) unsigned int*)(g + i*2048 + srcl),
                    (__attribute__((address_space(3))) unsigned int*)(l + i*1024 + (size_t)lane*16),
                    16, 0, 0);
            if (lane < 8)
                __builtin_amdgcn_global_load_lds(
                    (const __attribute__((address_space(1))) unsigned int*)(g + tsrcl),
                    (__attribute__((address_space(3))) unsigned int*)(l + 4096 + (size_t)lane*16),
                    16, 0, 0);
        }
    };

    f32x4 acc[4][4];
    auto ACCZERO = [&]() {
#pragma unroll
        for (int a = 0; a < 4; a++)
#pragma unroll
            for (int bq = 0; bq < 4; bq++)
                acc[a][bq] = (f32x4){0.f, 0.f, 0.f, 0.f};
    };

    // 9 taps of half-channel h from buffer buf (K=32 -> 1 MFMA per (Mt,Nt))
    auto COMPUTE = [&](int h, int buf) {
        const char* sb = (const char*)smem + buf*HBUF;
        const char* wbase = (const char*)wT + h*36864;   // wave-uniform
        __builtin_amdgcn_s_setprio(1);
#pragma unroll
        for (int tap = 0; tap < 9; tap++) {
            int dy = tap/3, dx = tap%3;
            const char* wtap = wbase + tap*4096;
            bf16x8 av[4], bv[4];
#pragma unroll
            for (int Mt = 0; Mt < 4; Mt++)
                av[Mt] = *reinterpret_cast<const bf16x8*>(
                    sb + vb[dx] + dy*HROWSTR + Mt*1024 + dx*64);
#pragma unroll
            for (int Nt = 0; Nt < 4; Nt++)
                bv[Nt] = *reinterpret_cast<const bf16x8*>(wtap + wvoff + Nt*256);
#pragma unroll
            for (int Mt = 0; Mt < 4; Mt++)
#pragma unroll
                for (int Nt = 0; Nt < 4; Nt++)
                    acc[Mt][Nt] = __builtin_amdgcn_mfma_f32_16x16x32_bf16(
                        bv[Nt], av[Mt], acc[Mt][Nt], 0, 0, 0);
        }
        __builtin_amdgcn_s_setprio(0);
    };

    // Epilogue for tile at row offset row128.
    // D layout: col(px-local)=m, row(co-local)=q*4+r.
    auto EPI = [&](int row128) {
        int yout = y0 + row128 + w;
        float4 bsv[4];
#pragma unroll
        for (int Nt = 0; Nt < 4; Nt++)
            bsv[Nt] = *reinterpret_cast<const float4*>(bias + Nt*16 + q*4);
        if (MODE == 1) {
            char* obase = (char*)outp +
                (((size_t)(n*NPAD + yout + 1))*NPAD + (X0 + 1))*128 + m*128 + q*8;
#pragma unroll
            for (int Mt = 0; Mt < 4; Mt++) {
                char* ob = obase + Mt*2048;
#pragma unroll
                for (int Nt = 0; Nt < 4; Nt++) {
                    float v0 = gelu_fast(acc[Mt][Nt][0] + bsv[Nt].x);
                    float v1 = gelu_fast(acc[Mt][Nt][1] + bsv[Nt].y);
                    float v2 = gelu_fast(acc[Mt][Nt][2] + bsv[Nt].z);
                    float v3 = gelu_fast(acc[Mt][Nt][3] + bsv[Nt].w);
                    uint2 pk = make_uint2(cvt_pk_bf16(v0, v1), cvt_pk_bf16(v2, v3));
                    *reinterpret_cast<uint2*>(ob + Nt*32) = pk;
                }
            }
        } else {
            char* obase = (char*)outp +
                (((size_t)(n*256 + yout))*256 + X0)*256 + m*256 + q*16;
#pragma unroll
            for (int Mt = 0; Mt < 4; Mt++) {
                char* ob = obase + Mt*4096;
#pragma unroll
                for (int Nt = 0; Nt < 4; Nt++) {
                    float4 v = make_float4(acc[Mt][Nt][0] + bsv[Nt].x,
                                           acc[Mt][Nt][1] + bsv[Nt].y,
                                           acc[Mt][Nt][2] + bsv[Nt].z,
                                           acc[Mt][Nt][3] + bsv[Nt].w);
                    *reinterpret_cast<float4*>(ob + Nt*64) = v;
                }
            }
        }
    };

    // ---- 4-step pipeline: (t0,h0) (t0,h1) (t1,h0) (t1,h1) ----
    ACCZERO();
    STAGE(0, 0, 0);
    __syncthreads();               // prologue drain (only fully-exposed stage)

    STAGE(0, 1, 1);                // prefetch (t0,h1) -> hidden under compute
    COMPUTE(0, 0);
    __syncthreads();

    STAGE(128, 0, 0);              // prefetch (t1,h0)
    COMPUTE(1, 1);
    EPI(0);
    ACCZERO();
    __syncthreads();

    STAGE(128, 1, 1);              // prefetch (t1,h1)
    COMPUTE(0, 0);
    __syncthreads();

    COMPUTE(1, 1);
    EPI(128);
}

extern "C" void kernel_launch(void* const* d_in, const int* in_sizes, int n_in,
                              void* d_out, int out_size, void* d_ws, size_t ws_size,
                              hipStream_t stream)
{
    const float* means = (const float*)d_in[0];
    const float* feats = (const float*)d_in[2];
    const float* intr  = (const float*)d_in[3];
    const float* extr  = (const float*)d_in[4];
    const float* w1    = (const float*)d_in[5];
    const float* b1    = (const float*)d_in[6];
    const float* w2    = (const float*)d_in[7];
    const float* b2    = (const float*)d_in[8];

    char* ws = (char*)d_ws;
    int*            counts = (int*)(ws + O_COUNTS);
    float*          w2c    = (float*)(ws + O_W2C);
    unsigned short* wT     = (unsigned short*)(ws + O_WT);
    int*            meta   = (int*)(ws + O_META);
    unsigned short* fusedP = (unsigned short*)(ws + O_FUSED);
    unsigned short* x1P    = (unsigned short*)(ws + O_X1);

    prep_kernel<<<dim3(96), dim3(256), 0, stream>>>(
        extr, w1, w2, w2c, wT, fusedP, x1P, counts);
    proj_kernel<<<dim3(256, 12), dim3(256), 0, stream>>>(
        means, intr, w2c, meta, counts);
    fuse_kernel<<<dim3(4096, 8), dim3(256), 0, stream>>>(
        feats, meta, counts, fusedP);
    conv_kernel<1><<<dim3(1024), dim3(256), 0, stream>>>(
        fusedP, wT, b1, (void*)x1P);
    conv_kernel<2><<<dim3(1024), dim3(256), 0, stream>>>(
        x1P, wT + 36864, b2, d_out);
}

// Round 11
// 376.064 us; speedup vs baseline: 1.2577x; 1.0121x over previous
//
#include <hip/hip_runtime.h>
#include <math.h>

// Problem constants
#define HW 65536          // 256*256
#define NPAD 258          // padded spatial dim

typedef short bf16x8 __attribute__((ext_vector_type(8)));
typedef float f32x4  __attribute__((ext_vector_type(4)));

// Workspace layout (bytes)
#define O_COUNTS 0            // 12 * 32 ints = 1536 B
#define O_W2C    2048         // 8 * 16 floats = 512 B
#define O_WT     4096         // 2 convs * 36864 bf16 = 147456 B  [cv][h][tap][q][co][8ci]
#define O_META   151552       // 12 * 65536 ints = 3 MiB
#define O_FUSED  3297280      // 8*258*258*64 bf16 = 68,161,536 B
#define O_X1     71458816     // same size

// Conv LDS: half-channel tile: 6 rows x 66 px x 64 B (32 ci). Two buffers.
#define HROWB   4224              // 66 px * 64 B
#define HROWSTR 4240
#define HBUF    25440             // 6 * HROWSTR, one buffer

__device__ __forceinline__ unsigned short f2bf(float f) {
    unsigned int u = __float_as_uint(f);
    u += 0x7FFFu + ((u >> 16) & 1u);   // round-to-nearest-even
    return (unsigned short)(u >> 16);
}

// Pack two f32 -> two bf16 in one u32 (RNE), single instruction.
__device__ __forceinline__ unsigned int cvt_pk_bf16(float lo, float hi) {
    unsigned int r;
    asm("v_cvt_pk_bf16_f32 %0, %1, %2" : "=v"(r) : "v"(lo), "v"(hi));
    return r;
}

// Fast erf-based GELU (Abramowitz-Stegun 7.1.26, |err_erf| <= 1.5e-7).
__device__ __forceinline__ float gelu_fast(float v) {
    float x  = v * 0.70710678118654752f;
    float ax = fabsf(x);
    float t  = __builtin_amdgcn_rcpf(fmaf(0.3275911f, ax, 1.0f));
    float p  = fmaf(t, 1.061405429f, -1.453152027f);
    p = fmaf(t, p, 1.421413741f);
    p = fmaf(t, p, -0.284496736f);
    p = fmaf(t, p, 0.254829592f);
    p = p * t;
    float e   = __expf(-x * x);
    float era = fmaf(-p, e, 1.0f);
    float er  = copysignf(era, x);
    return 0.5f * v * (1.0f + er);
}

// ---------------------------------------------------------------------------
// Prep: invert extrinsics, build bf16 weight fragment image [h][tap][q][co][8ci],
// zero padded-buffer borders, zero counts
// ---------------------------------------------------------------------------
__global__ __launch_bounds__(256) void prep_kernel(
    const float* __restrict__ extr, const float* __restrict__ w1,
    const float* __restrict__ w2, float* __restrict__ w2c,
    unsigned short* __restrict__ wT, unsigned short* __restrict__ fusedP,
    unsigned short* __restrict__ x1P, int* __restrict__ counts)
{
    int tid = blockIdx.x * blockDim.x + threadIdx.x;
    int nth = gridDim.x * blockDim.x;

    if (blockIdx.x == 0) {
        if (threadIdx.x < 8) {
            float a[4][8];
            const float* E = extr + threadIdx.x * 16;
            for (int r = 0; r < 4; r++)
                for (int c = 0; c < 4; c++) {
                    a[r][c] = E[r*4 + c];
                    a[r][4+c] = (r == c) ? 1.0f : 0.0f;
                }
            for (int col = 0; col < 4; col++) {
                int piv = col; float bm = fabsf(a[col][col]);
                for (int r = col+1; r < 4; r++) {
                    float v = fabsf(a[r][col]);
                    if (v > bm) { bm = v; piv = r; }
                }
                if (piv != col)
                    for (int c = 0; c < 8; c++) { float t = a[col][c]; a[col][c] = a[piv][c]; a[piv][c] = t; }
                float f = 1.0f / a[col][col];
                for (int c = 0; c < 8; c++) a[col][c] *= f;
                for (int r = 0; r < 4; r++) if (r != col) {
                    float f2 = a[r][col];
                    for (int c = 0; c < 8; c++) a[r][c] -= f2 * a[col][c];
                }
            }
            float* O = w2c + threadIdx.x * 16;
            for (int r = 0; r < 4; r++)
                for (int c = 0; c < 4; c++) O[r*4+c] = a[r][4+c];
        }
    }

    // Zero padded count slots (12 * 32 ints)
    for (int i = tid; i < 384; i += nth) counts[i] = 0;

    // Weight fragment image: 2 convs * [h2][tap9][q4][co64][j8]
    for (int e = tid; e < 73728; e += nth) {
        int t = e;
        int j  = t & 7;  t >>= 3;
        int co = t & 63; t >>= 6;
        int q  = t & 3;  t >>= 2;
        int tap = t % 9; t /= 9;
        int h  = t & 1;  int cv = t >> 1;
        int ci = h*32 + q*8 + j;
        int ky = tap / 3, kx = tap % 3;
        const float* wsrc = cv ? w2 : w1;
        float v = wsrc[((co*64 + ci)*3 + ky)*3 + kx];
        wT[cv*36864 + ((((h*9 + tap)*4 + q)*64 + co)*8 + j)] = f2bf(v);
    }

    // Zero borders of both padded buffers
    for (int u = tid; u < 2*8*1028*8; u += nth) {
        int t = u;
        int ch   = t & 7;    t >>= 3;
        int cell = t % 1028; t /= 1028;
        int n    = t & 7;    int buf = t >> 3;
        int y, x;
        if      (cell < 258) { y = 0;   x = cell; }
        else if (cell < 516) { y = 257; x = cell - 258; }
        else if (cell < 772) { y = cell - 516 + 1; x = 0; }
        else                 { y = cell - 772 + 1; x = 257; }
        unsigned short* p = (buf ? x1P : fusedP) +
            (((size_t)(n*NPAD + y)*NPAD + x)*64 + ch*8);
        *reinterpret_cast<uint4*>(p) = make_uint4(0u, 0u, 0u, 0u);
    }
}

// ---------------------------------------------------------------------------
// Projection: per (b, j->k) pair, compute mask|idx per point + valid counts.
// ---------------------------------------------------------------------------
__global__ __launch_bounds__(256) void proj_kernel(
    const float* __restrict__ means, const float* __restrict__ intr,
    const float* __restrict__ w2c, int* __restrict__ meta,
    int* __restrict__ counts)
{
    const int jt[6] = {0,1,1,2,2,3};
    const int kt[6] = {1,0,2,1,3,2};
    int s = blockIdx.y;            // 0..11
    int b = s / 6, p = s % 6;
    int j = jt[p], k = kt[p];
    int i = blockIdx.x * 256 + threadIdx.x;

    __shared__ int bcnt;
    if (threadIdx.x == 0) bcnt = 0;
    __syncthreads();

    const float* mp = means + ((size_t)(b*4 + j)*HW + i)*3;
    float x = mp[0], y = mp[1], z = mp[2];
    const float* M = w2c + (b*4 + k)*16;
    const float* I = intr + (b*4 + k)*9;

    float cx = fmaf(M[2],  z, fmaf(M[1], y, M[0]*x)) + M[3];
    float cy = fmaf(M[6],  z, fmaf(M[5], y, M[4]*x)) + M[7];
    float cz = fmaf(M[10], z, fmaf(M[9], y, M[8]*x)) + M[11];

    bool vz = cz > 1e-8f;
    float zi = cz + 1e-8f;
    float sx = cx / zi, sy = cy / zi, sz = cz / zi;
    float nx = fmaf(I[2], sz, fmaf(I[1], sy, I[0]*sx));
    float ny = fmaf(I[5], sz, fmaf(I[4], sy, I[3]*sx));

    int px = (int)floorf(nx * 256.0f);
    int py = (int)floorf(ny * 256.0f);
    bool mask = (nx >= 0.0f) && (nx < 1.0f) && (ny >= 0.0f) && (ny < 1.0f) && vz;
    int pxc = min(max(px, 0), 255);
    int pyc = min(max(py, 0), 255);
    int idx = pyc*256 + pxc;
    meta[(size_t)s*HW + i] = idx | (mask ? (int)0x80000000 : 0);

    unsigned long long bal = __ballot(mask ? 1 : 0);
    if ((threadIdx.x & 63) == 0)
        atomicAdd(&bcnt, (int)__popcll(bal));
    __syncthreads();
    if (threadIdx.x == 0)
        atomicAdd(counts + s*32, bcnt);
}

// ---------------------------------------------------------------------------
// Fusion v2: 2 points/thread (2 independent gather chains -> 2x MLP) and
// BRANCHLESS gathers: always load feats[k][mt&0xFFFF] (address always valid),
// weight by (mt<0 ? scale : 0). Removes the divergent mt<0 branch that
// serialized intra-wave (4 pts/wave share a branch; halves took turns) and
// lets all loads issue back-to-back. Extra gather traffic is L3-resident
// (feats = 134 MB < 256 MB L3). acc = feats_j + sum_k w*gather; /norm; bf16.
// ---------------------------------------------------------------------------
__global__ __launch_bounds__(256) void fuse_kernel(
    const float* __restrict__ feats, const int* __restrict__ meta,
    const int* __restrict__ counts, unsigned short* __restrict__ fusedP)
{
    const int nsl[4]    = {1, 2, 2, 1};
    const int slt[4][2] = {{0,0},{1,2},{3,4},{5,5}};
    const int kvw[4][2] = {{1,1},{0,2},{1,3},{2,2}};

    int bj = blockIdx.y;           // n = b*4 + j
    int b = bj >> 2, j = bj & 3;
    int base = blockIdx.x * 32;    // 32 points per block
    int cg = threadIdx.x & 15;
    int pt0 = base + (threadIdx.x >> 4);
    int pt1 = pt0 + 16;

    int ns = nsl[j];

    // Point 0 and point 1 state (independent chains; compiler interleaves).
    const float4* fj0 = reinterpret_cast<const float4*>(
        feats + ((size_t)bj*HW + pt0)*64) + cg;
    const float4* fj1 = reinterpret_cast<const float4*>(
        feats + ((size_t)bj*HW + pt1)*64) + cg;
    float4 acc0 = *fj0;
    float4 acc1 = *fj1;
    float norm = 1.0f;             // same for both points (count-based)

#pragma unroll
    for (int e = 0; e < 2; e++) {
        if (e < ns) {
            int p = slt[j][e], k = kvw[j][e];
            int s = b*6 + p;
            float scale = 0.1f * (float)counts[s*32] / 65536.0f;
            int mt0 = meta[(size_t)s*HW + pt0];
            int mt1 = meta[(size_t)s*HW + pt1];
            // Branchless: always gather (clamped-valid idx), zero the weight.
            const float* fk = feats + (size_t)(b*4 + k)*HW*64;
            float4 g0 = *(reinterpret_cast<const float4*>(
                fk + (size_t)(mt0 & 0xFFFF)*64) + cg);
            float4 g1 = *(reinterpret_cast<const float4*>(
                fk + (size_t)(mt1 & 0xFFFF)*64) + cg);
            float w0 = (mt0 < 0) ? scale : 0.0f;
            float w1 = (mt1 < 0) ? scale : 0.0f;
            acc0.x = fmaf(w0, g0.x, acc0.x); acc0.y = fmaf(w0, g0.y, acc0.y);
            acc0.z = fmaf(w0, g0.z, acc0.z); acc0.w = fmaf(w0, g0.w, acc0.w);
            acc1.x = fmaf(w1, g1.x, acc1.x); acc1.y = fmaf(w1, g1.y, acc1.y);
            acc1.z = fmaf(w1, g1.z, acc1.z); acc1.w = fmaf(w1, g1.w, acc1.w);
            norm += scale;
        }
    }
    float rn = 1.0f / norm;

    int yy0 = pt0 >> 8, xx0 = pt0 & 255;
    unsigned short* op0 = fusedP +
        (((size_t)bj*NPAD + (yy0+1))*NPAD + (xx0+1))*64 + cg*4;
    *reinterpret_cast<uint2*>(op0) =
        make_uint2(cvt_pk_bf16(acc0.x*rn, acc0.y*rn),
                   cvt_pk_bf16(acc0.z*rn, acc0.w*rn));

    int yy1 = pt1 >> 8, xx1 = pt1 & 255;
    unsigned short* op1 = fusedP +
        (((size_t)bj*NPAD + (yy1+1))*NPAD + (xx1+1))*64 + cg*4;
    *reinterpret_cast<uint2*>(op1) =
        make_uint2(cvt_pk_bf16(acc1.x*rn, acc1.y*rn),
                   cvt_pk_bf16(acc1.z*rn, acc1.w*rn));
}

// ---------------------------------------------------------------------------
// 3x3 conv, 2-tile pipelined (r6 structure — best measured; desync removed,
// it was neutral). Tiles t0 (rows y0..y0+3) and t1 (y0+128..) of one image
// (XCD map: image = fid&7), 4 half-channel steps over two 25.4 KB LDS
// buffers, each step prefetching the next half-tile via global_load_lds
// (16B, pre-swizzled global source; LDS slot (px,c) holds chunk c^((px>>1)&3)).
// MFMA operands swapped (weights=A, pixels=B) -> 4 contiguous co per lane ->
// vectorized stores. Weight loads saddr-form. No min-waves pin (r3: spills).
// Reg-staging worse (r9: VGPR 132 occupancy cliff). Counted-vmcnt worse (r7:
// 2 blocks/CU trade). 8-wave split neutral (r8). Desync neutral (r10).
// ---------------------------------------------------------------------------
template<int MODE>
__global__ __launch_bounds__(256) void conv_kernel(
    const unsigned short* __restrict__ in, const unsigned short* __restrict__ wT,
    const float* __restrict__ bias, void* __restrict__ outp)
{
    __shared__ unsigned short smem[2 * HBUF / 2];   // 50880 B = two buffers

    int fid = blockIdx.x;          // 0..1023
    int n   = fid & 7;             // image 0..7
    int rem = fid >> 3;            // 0..127
    int y0  = (rem >> 2) << 2;     // 0..124
    int X0  = (rem & 3) << 6;      // 0,64,128,192

    int w  = threadIdx.x >> 6;     // wave id: output row y0+w
    int lane = threadIdx.x & 63;
    int m = lane & 15, q = lane >> 4;

    // Staging per-lane source offsets (relative to a (row, h) strip base).
    int srcl = ((lane >> 2) * 128) + ((((lane & 3) ^ ((lane >> 3) & 3)) & 3) << 4);
    int tsrcl = 8192 + ((lane >> 2) * 128) + ((lane & 3) << 4);

    // ds_read per-lane bases (one per dx; q fixed per lane so XOR collapses).
    int vb[3];
#pragma unroll
    for (int dx = 0; dx < 3; dx++)
        vb[dx] = w*HROWSTR + m*64 + (((q ^ (((m + dx) >> 1) & 3)) & 3) << 4);

    int wvoff = q*1024 + m*16;     // per-lane weight fragment offset (bytes)

    const char* gb00 = (const char*)in +
        (((size_t)(n*NPAD) + y0) * NPAD + X0) * 128;

    // Stage half-channel h of tile at row offset row128 into buffer buf.
    auto STAGE = [&](int row128, int h, int buf) {
        const char* gb = gb00 + (size_t)row128 * (NPAD*128) + h*64;
        char* lb = (char*)smem + buf*HBUF;
        for (int ri = w; ri < 6; ri += 4) {
            const char* g = gb + (size_t)ri * (NPAD*128);
            char* l = lb + ri*HROWSTR;
#pragma unroll
            for (int i = 0; i < 4; i++)
                __builtin_amdgcn_global_load_lds(
                    (const __attribute__((address_space(1))) unsigned int*)(g + i*2048 + srcl),
                    (__attribute__((address_space(3))) unsigned int*)(l + i*1024 + (size_t)lane*16),
                    16, 0, 0);
            if (lane < 8)
                __builtin_amdgcn_global_load_lds(
                    (const __attribute__((address_space(1))) unsigned int*)(g + tsrcl),
                    (__attribute__((address_space(3))) unsigned int*)(l + 4096 + (size_t)lane*16),
                    16, 0, 0);
        }
    };

    f32x4 acc[4][4];
    auto ACCZERO = [&]() {
#pragma unroll
        for (int a = 0; a < 4; a++)
#pragma unroll
            for (int bq = 0; bq < 4; bq++)
                acc[a][bq] = (f32x4){0.f, 0.f, 0.f, 0.f};
    };

    // 9 taps of half-channel h from buffer buf (K=32 -> 1 MFMA per (Mt,Nt))
    auto COMPUTE = [&](int h, int buf) {
        const char* sb = (const char*)smem + buf*HBUF;
        const char* wbase = (const char*)wT + h*36864;   // wave-uniform
        __builtin_amdgcn_s_setprio(1);
#pragma unroll
        for (int tap = 0; tap < 9; tap++) {
            int dy = tap/3, dx = tap%3;
            const char* wtap = wbase + tap*4096;
            bf16x8 av[4], bv[4];
#pragma unroll
            for (int Mt = 0; Mt < 4; Mt++)
                av[Mt] = *reinterpret_cast<const bf16x8*>(
                    sb + vb[dx] + dy*HROWSTR + Mt*1024 + dx*64);
#pragma unroll
            for (int Nt = 0; Nt < 4; Nt++)
                bv[Nt] = *reinterpret_cast<const bf16x8*>(wtap + wvoff + Nt*256);
#pragma unroll
            for (int Mt = 0; Mt < 4; Mt++)
#pragma unroll
                for (int Nt = 0; Nt < 4; Nt++)
                    acc[Mt][Nt] = __builtin_amdgcn_mfma_f32_16x16x32_bf16(
                        bv[Nt], av[Mt], acc[Mt][Nt], 0, 0, 0);
        }
        __builtin_amdgcn_s_setprio(0);
    };

    // Epilogue for tile at row offset row128.
    // D layout: col(px-local)=m, row(co-local)=q*4+r.
    auto EPI = [&](int row128) {
        int yout = y0 + row128 + w;
        float4 bsv[4];
#pragma unroll
        for (int Nt = 0; Nt < 4; Nt++)
            bsv[Nt] = *reinterpret_cast<const float4*>(bias + Nt*16 + q*4);
        if (MODE == 1) {
            char* obase = (char*)outp +
                (((size_t)(n*NPAD + yout + 1))*NPAD + (X0 + 1))*128 + m*128 + q*8;
#pragma unroll
            for (int Mt = 0; Mt < 4; Mt++) {
                char* ob = obase + Mt*2048;
#pragma unroll
                for (int Nt = 0; Nt < 4; Nt++) {
                    float v0 = gelu_fast(acc[Mt][Nt][0] + bsv[Nt].x);
                    float v1 = gelu_fast(acc[Mt][Nt][1] + bsv[Nt].y);
                    float v2 = gelu_fast(acc[Mt][Nt][2] + bsv[Nt].z);
                    float v3 = gelu_fast(acc[Mt][Nt][3] + bsv[Nt].w);
                    uint2 pk = make_uint2(cvt_pk_bf16(v0, v1), cvt_pk_bf16(v2, v3));
                    *reinterpret_cast<uint2*>(ob + Nt*32) = pk;
                }
            }
        } else {
            char* obase = (char*)outp +
                (((size_t)(n*256 + yout))*256 + X0)*256 + m*256 + q*16;
#pragma unroll
            for (int Mt = 0; Mt < 4; Mt++) {
                char* ob = obase + Mt*4096;
#pragma unroll
                for (int Nt = 0; Nt < 4; Nt++) {
                    float4 v = make_float4(acc[Mt][Nt][0] + bsv[Nt].x,
                                           acc[Mt][Nt][1] + bsv[Nt].y,
                                           acc[Mt][Nt][2] + bsv[Nt].z,
                                           acc[Mt][Nt][3] + bsv[Nt].w);
                    *reinterpret_cast<float4*>(ob + Nt*64) = v;
                }
            }
        }
    };

    // ---- 4-step pipeline: (t0,h0) (t0,h1) (t1,h0) (t1,h1) ----
    ACCZERO();
    STAGE(0, 0, 0);
    __syncthreads();               // prologue drain (only fully-exposed stage)

    STAGE(0, 1, 1);                // prefetch (t0,h1) -> hidden under compute
    COMPUTE(0, 0);
    __syncthreads();

    STAGE(128, 0, 0);              // prefetch (t1,h0)
    COMPUTE(1, 1);
    EPI(0);
    ACCZERO();
    __syncthreads();

    STAGE(128, 1, 1);              // prefetch (t1,h1)
    COMPUTE(0, 0);
    __syncthreads();

    COMPUTE(1, 1);
    EPI(128);
}

extern "C" void kernel_launch(void* const* d_in, const int* in_sizes, int n_in,
                              void* d_out, int out_size, void* d_ws, size_t ws_size,
                              hipStream_t stream)
{
    const float* means = (const float*)d_in[0];
    const float* feats = (const float*)d_in[2];
    const float* intr  = (const float*)d_in[3];
    const float* extr  = (const float*)d_in[4];
    const float* w1    = (const float*)d_in[5];
    const float* b1    = (const float*)d_in[6];
    const float* w2    = (const float*)d_in[7];
    const float* b2    = (const float*)d_in[8];

    char* ws = (char*)d_ws;
    int*            counts = (int*)(ws + O_COUNTS);
    float*          w2c    = (float*)(ws + O_W2C);
    unsigned short* wT     = (unsigned short*)(ws + O_WT);
    int*            meta   = (int*)(ws + O_META);
    unsigned short* fusedP = (unsigned short*)(ws + O_FUSED);
    unsigned short* x1P    = (unsigned short*)(ws + O_X1);

    prep_kernel<<<dim3(96), dim3(256), 0, stream>>>(
        extr, w1, w2, w2c, wT, fusedP, x1P, counts);
    proj_kernel<<<dim3(256, 12), dim3(256), 0, stream>>>(
        means, intr, w2c, meta, counts);
    fuse_kernel<<<dim3(2048, 8), dim3(256), 0, stream>>>(
        feats, meta, counts, fusedP);
    conv_kernel<1><<<dim3(1024), dim3(256), 0, stream>>>(
        fusedP, wT, b1, (void*)x1P);
    conv_kernel<2><<<dim3(1024), dim3(256), 0, stream>>>(
        x1P, wT + 36864, b2, d_out);
}

// Round 12
// 355.579 us; speedup vs baseline: 1.3301x; 1.0576x over previous
//
#include <hip/hip_runtime.h>
#include <math.h>

// Problem constants
#define HW 65536          // 256*256
#define NPAD 258          // padded spatial dim

typedef short bf16x8 __attribute__((ext_vector_type(8)));
typedef float f32x4  __attribute__((ext_vector_type(4)));

// Workspace layout (bytes)
#define O_COUNTS 0            // 12 * 32 ints = 1536 B
#define O_W2C    2048         // 8 * 16 floats = 512 B
#define O_WT     4096         // 2 convs * 36864 bf16 = 147456 B  [cv][h][tap][q][co][8ci]
#define O_META   151552       // 12 * 65536 ints = 3 MiB
#define O_FUSED  3297280      // 8*258*258*64 bf16 = 68,161,536 B
#define O_X1     71458816     // same size

// Conv LDS: pixel half-channel tile 6 rows x 66 px x 64 B (single buffer)
// + weight image for the current half (9 taps x 4 KB).
#define HROWB   4224              // 66 px * 64 B
#define HROWSTR 4240
#define PXBUF   25440             // 6 * HROWSTR
#define WBUF    36864             // 9 * 4096

__device__ __forceinline__ unsigned short f2bf(float f) {
    unsigned int u = __float_as_uint(f);
    u += 0x7FFFu + ((u >> 16) & 1u);   // round-to-nearest-even
    return (unsigned short)(u >> 16);
}

// Pack two f32 -> two bf16 in one u32 (RNE), single instruction.
__device__ __forceinline__ unsigned int cvt_pk_bf16(float lo, float hi) {
    unsigned int r;
    asm("v_cvt_pk_bf16_f32 %0, %1, %2" : "=v"(r) : "v"(lo), "v"(hi));
    return r;
}

// Fast erf-based GELU (Abramowitz-Stegun 7.1.26, |err_erf| <= 1.5e-7).
__device__ __forceinline__ float gelu_fast(float v) {
    float x  = v * 0.70710678118654752f;
    float ax = fabsf(x);
    float t  = __builtin_amdgcn_rcpf(fmaf(0.3275911f, ax, 1.0f));
    float p  = fmaf(t, 1.061405429f, -1.453152027f);
    p = fmaf(t, p, 1.421413741f);
    p = fmaf(t, p, -0.284496736f);
    p = fmaf(t, p, 0.254829592f);
    p = p * t;
    float e   = __expf(-x * x);
    float era = fmaf(-p, e, 1.0f);
    float er  = copysignf(era, x);
    return 0.5f * v * (1.0f + er);
}

// ---------------------------------------------------------------------------
// Prep: invert extrinsics, build bf16 weight fragment image [h][tap][q][co][8ci],
// zero padded-buffer borders, zero counts
// ---------------------------------------------------------------------------
__global__ __launch_bounds__(256) void prep_kernel(
    const float* __restrict__ extr, const float* __restrict__ w1,
    const float* __restrict__ w2, float* __restrict__ w2c,
    unsigned short* __restrict__ wT, unsigned short* __restrict__ fusedP,
    unsigned short* __restrict__ x1P, int* __restrict__ counts)
{
    int tid = blockIdx.x * blockDim.x + threadIdx.x;
    int nth = gridDim.x * blockDim.x;

    if (blockIdx.x == 0) {
        if (threadIdx.x < 8) {
            float a[4][8];
            const float* E = extr + threadIdx.x * 16;
            for (int r = 0; r < 4; r++)
                for (int c = 0; c < 4; c++) {
                    a[r][c] = E[r*4 + c];
                    a[r][4+c] = (r == c) ? 1.0f : 0.0f;
                }
            for (int col = 0; col < 4; col++) {
                int piv = col; float bm = fabsf(a[col][col]);
                for (int r = col+1; r < 4; r++) {
                    float v = fabsf(a[r][col]);
                    if (v > bm) { bm = v; piv = r; }
                }
                if (piv != col)
                    for (int c = 0; c < 8; c++) { float t = a[col][c]; a[col][c] = a[piv][c]; a[piv][c] = t; }
                float f = 1.0f / a[col][col];
                for (int c = 0; c < 8; c++) a[col][c] *= f;
                for (int r = 0; r < 4; r++) if (r != col) {
                    float f2 = a[r][col];
                    for (int c = 0; c < 8; c++) a[r][c] -= f2 * a[col][c];
                }
            }
            float* O = w2c + threadIdx.x * 16;
            for (int r = 0; r < 4; r++)
                for (int c = 0; c < 4; c++) O[r*4+c] = a[r][4+c];
        }
    }

    // Zero padded count slots (12 * 32 ints)
    for (int i = tid; i < 384; i += nth) counts[i] = 0;

    // Weight fragment image: 2 convs * [h2][tap9][q4][co64][j8]
    for (int e = tid; e < 73728; e += nth) {
        int t = e;
        int j  = t & 7;  t >>= 3;
        int co = t & 63; t >>= 6;
        int q  = t & 3;  t >>= 2;
        int tap = t % 9; t /= 9;
        int h  = t & 1;  int cv = t >> 1;
        int ci = h*32 + q*8 + j;
        int ky = tap / 3, kx = tap % 3;
        const float* wsrc = cv ? w2 : w1;
        float v = wsrc[((co*64 + ci)*3 + ky)*3 + kx];
        wT[cv*36864 + ((((h*9 + tap)*4 + q)*64 + co)*8 + j)] = f2bf(v);
    }

    // Zero borders of both padded buffers
    for (int u = tid; u < 2*8*1028*8; u += nth) {
        int t = u;
        int ch   = t & 7;    t >>= 3;
        int cell = t % 1028; t /= 1028;
        int n    = t & 7;    int buf = t >> 3;
        int y, x;
        if      (cell < 258) { y = 0;   x = cell; }
        else if (cell < 516) { y = 257; x = cell - 258; }
        else if (cell < 772) { y = cell - 516 + 1; x = 0; }
        else                 { y = cell - 772 + 1; x = 257; }
        unsigned short* p = (buf ? x1P : fusedP) +
            (((size_t)(n*NPAD + y)*NPAD + x)*64 + ch*8);
        *reinterpret_cast<uint4*>(p) = make_uint4(0u, 0u, 0u, 0u);
    }
}

// ---------------------------------------------------------------------------
// Projection: per (b, j->k) pair, compute mask|idx per point + valid counts.
// ---------------------------------------------------------------------------
__global__ __launch_bounds__(256) void proj_kernel(
    const float* __restrict__ means, const float* __restrict__ intr,
    const float* __restrict__ w2c, int* __restrict__ meta,
    int* __restrict__ counts)
{
    const int jt[6] = {0,1,1,2,2,3};
    const int kt[6] = {1,0,2,1,3,2};
    int s = blockIdx.y;            // 0..11
    int b = s / 6, p = s % 6;
    int j = jt[p], k = kt[p];
    int i = blockIdx.x * 256 + threadIdx.x;

    __shared__ int bcnt;
    if (threadIdx.x == 0) bcnt = 0;
    __syncthreads();

    const float* mp = means + ((size_t)(b*4 + j)*HW + i)*3;
    float x = mp[0], y = mp[1], z = mp[2];
    const float* M = w2c + (b*4 + k)*16;
    const float* I = intr + (b*4 + k)*9;

    float cx = fmaf(M[2],  z, fmaf(M[1], y, M[0]*x)) + M[3];
    float cy = fmaf(M[6],  z, fmaf(M[5], y, M[4]*x)) + M[7];
    float cz = fmaf(M[10], z, fmaf(M[9], y, M[8]*x)) + M[11];

    bool vz = cz > 1e-8f;
    float zi = cz + 1e-8f;
    float sx = cx / zi, sy = cy / zi, sz = cz / zi;
    float nx = fmaf(I[2], sz, fmaf(I[1], sy, I[0]*sx));
    float ny = fmaf(I[5], sz, fmaf(I[4], sy, I[3]*sx));

    int px = (int)floorf(nx * 256.0f);
    int py = (int)floorf(ny * 256.0f);
    bool mask = (nx >= 0.0f) && (nx < 1.0f) && (ny >= 0.0f) && (ny < 1.0f) && vz;
    int pxc = min(max(px, 0), 255);
    int pyc = min(max(py, 0), 255);
    int idx = pyc*256 + pxc;
    meta[(size_t)s*HW + i] = idx | (mask ? (int)0x80000000 : 0);

    unsigned long long bal = __ballot(mask ? 1 : 0);
    if ((threadIdx.x & 63) == 0)
        atomicAdd(&bcnt, (int)__popcll(bal));
    __syncthreads();
    if (threadIdx.x == 0)
        atomicAdd(counts + s*32, bcnt);
}

// ---------------------------------------------------------------------------
// Fusion v2 (r11, kept): 2 points/thread, branchless gathers.
// ---------------------------------------------------------------------------
__global__ __launch_bounds__(256) void fuse_kernel(
    const float* __restrict__ feats, const int* __restrict__ meta,
    const int* __restrict__ counts, unsigned short* __restrict__ fusedP)
{
    const int nsl[4]    = {1, 2, 2, 1};
    const int slt[4][2] = {{0,0},{1,2},{3,4},{5,5}};
    const int kvw[4][2] = {{1,1},{0,2},{1,3},{2,2}};

    int bj = blockIdx.y;           // n = b*4 + j
    int b = bj >> 2, j = bj & 3;
    int base = blockIdx.x * 32;    // 32 points per block
    int cg = threadIdx.x & 15;
    int pt0 = base + (threadIdx.x >> 4);
    int pt1 = pt0 + 16;

    int ns = nsl[j];

    const float4* fj0 = reinterpret_cast<const float4*>(
        feats + ((size_t)bj*HW + pt0)*64) + cg;
    const float4* fj1 = reinterpret_cast<const float4*>(
        feats + ((size_t)bj*HW + pt1)*64) + cg;
    float4 acc0 = *fj0;
    float4 acc1 = *fj1;
    float norm = 1.0f;

#pragma unroll
    for (int e = 0; e < 2; e++) {
        if (e < ns) {
            int p = slt[j][e], k = kvw[j][e];
            int s = b*6 + p;
            float scale = 0.1f * (float)counts[s*32] / 65536.0f;
            int mt0 = meta[(size_t)s*HW + pt0];
            int mt1 = meta[(size_t)s*HW + pt1];
            const float* fk = feats + (size_t)(b*4 + k)*HW*64;
            float4 g0 = *(reinterpret_cast<const float4*>(
                fk + (size_t)(mt0 & 0xFFFF)*64) + cg);
            float4 g1 = *(reinterpret_cast<const float4*>(
                fk + (size_t)(mt1 & 0xFFFF)*64) + cg);
            float w0 = (mt0 < 0) ? scale : 0.0f;
            float w1 = (mt1 < 0) ? scale : 0.0f;
            acc0.x = fmaf(w0, g0.x, acc0.x); acc0.y = fmaf(w0, g0.y, acc0.y);
            acc0.z = fmaf(w0, g0.z, acc0.z); acc0.w = fmaf(w0, g0.w, acc0.w);
            acc1.x = fmaf(w1, g1.x, acc1.x); acc1.y = fmaf(w1, g1.y, acc1.y);
            acc1.z = fmaf(w1, g1.z, acc1.z); acc1.w = fmaf(w1, g1.w, acc1.w);
            norm += scale;
        }
    }
    float rn = 1.0f / norm;

    int yy0 = pt0 >> 8, xx0 = pt0 & 255;
    unsigned short* op0 = fusedP +
        (((size_t)bj*NPAD + (yy0+1))*NPAD + (xx0+1))*64 + cg*4;
    *reinterpret_cast<uint2*>(op0) =
        make_uint2(cvt_pk_bf16(acc0.x*rn, acc0.y*rn),
                   cvt_pk_bf16(acc0.z*rn, acc0.w*rn));

    int yy1 = pt1 >> 8, xx1 = pt1 & 255;
    unsigned short* op1 = fusedP +
        (((size_t)bj*NPAD + (yy1+1))*NPAD + (xx1+1))*64 + cg*4;
    *reinterpret_cast<uint2*>(op1) =
        make_uint2(cvt_pk_bf16(acc1.x*rn, acc1.y*rn),
                   cvt_pk_bf16(acc1.z*rn, acc1.w*rn));
}

// ---------------------------------------------------------------------------
// 3x3 conv, WEIGHTS-IN-LDS probe: the per-half weight image (36,864 B) is
// larger than the 32 KiB L1, so in all prior variants every per-tap weight
// load was an L2 hit (~200-900 cyc) on the MFMA critical path, re-fetched by
// every wave — the last unfalsified mechanism for conv's ~54 µs latency gap.
// This version stages the current half's weights into LDS once per half.
//
// LDS weight layout [tap][NtG][lane*16B]: both the global_load_lds DEST and
// the ds_read_b128 are exactly linear-per-lane (conflict-free); the global
// SOURCE permutation reuses the wvoff+i*256 per-lane pattern (bijective:
// lds chunk (NtG,q,m) <- global chunk q*64+NtG*16+m).
//
// Block = 8 waves (512 thr, r8 split: row=w&3, co-half cH=w>>2, acc[4][2]).
// LDS = PXBUF 25.4 KB (single pixel buffer) + WBUF 36.9 KB = 62.3 KB ->
// 2 blocks/CU = 16 waves/CU (same residency as r6). h-outer ordering:
// weights staged 2x/block; both tiles' acc live as NAMED arrays (rule #20).
// Pixel staging: waves 0-5 (one row each); weight staging: waves 6-7.
// ---------------------------------------------------------------------------
template<int MODE>
__global__ __launch_bounds__(512) void conv_kernel(
    const unsigned short* __restrict__ in, const unsigned short* __restrict__ wT,
    const float* __restrict__ bias, void* __restrict__ outp)
{
    __shared__ unsigned short smem[(PXBUF + WBUF) / 2];
    unsigned short* wlds = smem + PXBUF/2;

    int fid = blockIdx.x;          // 0..1023
    int n   = fid & 7;             // image 0..7 (XCD map)
    int rem = fid >> 3;            // 0..127
    int y0  = (rem >> 2) << 2;     // 0..124
    int X0  = (rem & 3) << 6;      // 0,64,128,192

    int w    = threadIdx.x >> 6;   // wave id 0..7
    int row  = w & 3;              // output row y0+row
    int cH   = w >> 2;             // co-half
    int lane = threadIdx.x & 63;
    int m = lane & 15, q = lane >> 4;

    // Pixel staging per-lane source offsets (pre-swizzled global).
    int srcl = ((lane >> 2) * 128) + ((((lane & 3) ^ ((lane >> 3) & 3)) & 3) << 4);
    int tsrcl = 8192 + ((lane >> 2) * 128) + ((lane & 3) << 4);

    // ds_read per-lane pixel bases (one per dx).
    int vb[3];
#pragma unroll
    for (int dx = 0; dx < 3; dx++)
        vb[dx] = row*HROWSTR + m*64 + (((q ^ (((m + dx) >> 1) & 3)) & 3) << 4);

    int wvoff = q*1024 + m*16;     // per-lane weight source offset (bytes)

    const char* gb00 = (const char*)in +
        (((size_t)(n*NPAD) + y0) * NPAD + X0) * 128;

    // Stage pixel half-channel h of tile at row offset row128 (waves 0-5).
    auto STAGE_PX = [&](int row128, int h) {
        if (w < 6) {
            const char* g = gb00 + (size_t)row128 * (NPAD*128) + h*64
                          + (size_t)w * (NPAD*128);
            char* l = (char*)smem + w*HROWSTR;
#pragma unroll
            for (int i = 0; i < 4; i++)
                __builtin_amdgcn_global_load_lds(
                    (const __attribute__((address_space(1))) unsigned int*)(g + i*2048 + srcl),
                    (__attribute__((address_space(3))) unsigned int*)(l + i*1024 + (size_t)lane*16),
                    16, 0, 0);
            if (lane < 8)
                __builtin_amdgcn_global_load_lds(
                    (const __attribute__((address_space(1))) unsigned int*)(g + tsrcl),
                    (__attribute__((address_space(3))) unsigned int*)(l + 4096 + (size_t)lane*16),
                    16, 0, 0);
        }
    };

    // Stage half-h weights into wlds (waves 6,7). LDS dest linear per lane;
    // global source = wT + h*36864 + tap*4096 + i*256 + wvoff.
    auto STAGE_W = [&](int h) {
        const char* wh = (const char*)wT + h*36864 + wvoff;
        char* ld = (char*)wlds + (size_t)lane*16;
        if (w == 6) {
#pragma unroll
            for (int tap = 0; tap < 4; tap++)
#pragma unroll
                for (int i = 0; i < 4; i++)
                    __builtin_amdgcn_global_load_lds(
                        (const __attribute__((address_space(1))) unsigned int*)(wh + tap*4096 + i*256),
                        (__attribute__((address_space(3))) unsigned int*)(ld + tap*4096 + i*1024),
                        16, 0, 0);
        } else if (w == 7) {
#pragma unroll
            for (int tap = 4; tap < 9; tap++)
#pragma unroll
                for (int i = 0; i < 4; i++)
                    __builtin_amdgcn_global_load_lds(
                        (const __attribute__((address_space(1))) unsigned int*)(wh + tap*4096 + i*256),
                        (__attribute__((address_space(3))) unsigned int*)(ld + tap*4096 + i*1024),
                        16, 0, 0);
        }
    };

    // 9 taps from the pixel buffer + LDS weights into acc (this wave's 2 Nt).
    auto COMPUTE = [&](f32x4 (&acc)[4][2]) {
        const char* sb = (const char*)smem;
        const char* wb = (const char*)wlds + (size_t)lane*16 + cH*2048;
        __builtin_amdgcn_s_setprio(1);
#pragma unroll
        for (int tap = 0; tap < 9; tap++) {
            int dy = tap/3, dx = tap%3;
            bf16x8 av[4], bv[2];
#pragma unroll
            for (int Mt = 0; Mt < 4; Mt++)
                av[Mt] = *reinterpret_cast<const bf16x8*>(
                    sb + vb[dx] + dy*HROWSTR + Mt*1024 + dx*64);
#pragma unroll
            for (int Nt = 0; Nt < 2; Nt++)
                bv[Nt] = *reinterpret_cast<const bf16x8*>(wb + tap*4096 + Nt*1024);
#pragma unroll
            for (int Mt = 0; Mt < 4; Mt++)
#pragma unroll
                for (int Nt = 0; Nt < 2; Nt++)
                    acc[Mt][Nt] = __builtin_amdgcn_mfma_f32_16x16x32_bf16(
                        bv[Nt], av[Mt], acc[Mt][Nt], 0, 0, 0);
        }
        __builtin_amdgcn_s_setprio(0);
    };

    // Epilogue. D: col(px)=m, row(co-local)=q*4+r; co = cH*32 + Nt*16 + q*4.
    auto EPI = [&](int row128, f32x4 (&acc)[4][2]) {
        int yout = y0 + row128 + row;
        float4 bsv[2];
#pragma unroll
        for (int Nt = 0; Nt < 2; Nt++)
            bsv[Nt] = *reinterpret_cast<const float4*>(bias + cH*32 + Nt*16 + q*4);
        if (MODE == 1) {
            char* obase = (char*)outp +
                (((size_t)(n*NPAD + yout + 1))*NPAD + (X0 + 1))*128 + m*128 + q*8 + cH*64;
#pragma unroll
            for (int Mt = 0; Mt < 4; Mt++) {
                char* ob = obase + Mt*2048;
#pragma unroll
                for (int Nt = 0; Nt < 2; Nt++) {
                    float v0 = gelu_fast(acc[Mt][Nt][0] + bsv[Nt].x);
                    float v1 = gelu_fast(acc[Mt][Nt][1] + bsv[Nt].y);
                    float v2 = gelu_fast(acc[Mt][Nt][2] + bsv[Nt].z);
                    float v3 = gelu_fast(acc[Mt][Nt][3] + bsv[Nt].w);
                    uint2 pk = make_uint2(cvt_pk_bf16(v0, v1), cvt_pk_bf16(v2, v3));
                    *reinterpret_cast<uint2*>(ob + Nt*32) = pk;
                }
            }
        } else {
            char* obase = (char*)outp +
                (((size_t)(n*256 + yout))*256 + X0)*256 + m*256 + q*16 + cH*128;
#pragma unroll
            for (int Mt = 0; Mt < 4; Mt++) {
                char* ob = obase + Mt*4096;
#pragma unroll
                for (int Nt = 0; Nt < 2; Nt++) {
                    float4 v = make_float4(acc[Mt][Nt][0] + bsv[Nt].x,
                                           acc[Mt][Nt][1] + bsv[Nt].y,
                                           acc[Mt][Nt][2] + bsv[Nt].z,
                                           acc[Mt][Nt][3] + bsv[Nt].w);
                    *reinterpret_cast<float4*>(ob + Nt*64) = v;
                }
            }
        }
    };

    f32x4 accA[4][2], accB[4][2];
#pragma unroll
    for (int a = 0; a < 4; a++)
#pragma unroll
        for (int bq = 0; bq < 2; bq++) {
            accA[a][bq] = (f32x4){0.f, 0.f, 0.f, 0.f};
            accB[a][bq] = (f32x4){0.f, 0.f, 0.f, 0.f};
        }

    // ---- h-outer schedule: weights staged once per half, 2 tiles each ----
    STAGE_W(0); STAGE_PX(0, 0);
    __syncthreads();               // px(t0,h0) + w(h0) ready

    COMPUTE(accA);
    __syncthreads();               // px buffer free

    STAGE_PX(128, 0);
    __syncthreads();               // px(t1,h0) ready

    COMPUTE(accB);
    __syncthreads();               // px + w(h0) free

    STAGE_W(1); STAGE_PX(0, 1);
    __syncthreads();

    COMPUTE(accA);
    __syncthreads();

    STAGE_PX(128, 1);
    EPI(0, accA);                  // epilogue overlaps the px stage
    __syncthreads();

    COMPUTE(accB);
    EPI(128, accB);
}

extern "C" void kernel_launch(void* const* d_in, const int* in_sizes, int n_in,
                              void* d_out, int out_size, void* d_ws, size_t ws_size,
                              hipStream_t stream)
{
    const float* means = (const float*)d_in[0];
    const float* feats = (const float*)d_in[2];
    const float* intr  = (const float*)d_in[3];
    const float* extr  = (const float*)d_in[4];
    const float* w1    = (const float*)d_in[5];
    const float* b1    = (const float*)d_in[6];
    const float* w2    = (const float*)d_in[7];
    const float* b2    = (const float*)d_in[8];

    char* ws = (char*)d_ws;
    int*            counts = (int*)(ws + O_COUNTS);
    float*          w2c    = (float*)(ws + O_W2C);
    unsigned short* wT     = (unsigned short*)(ws + O_WT);
    int*            meta   = (int*)(ws + O_META);
    unsigned short* fusedP = (unsigned short*)(ws + O_FUSED);
    unsigned short* x1P    = (unsigned short*)(ws + O_X1);

    prep_kernel<<<dim3(96), dim3(256), 0, stream>>>(
        extr, w1, w2, w2c, wT, fusedP, x1P, counts);
    proj_kernel<<<dim3(256, 12), dim3(256), 0, stream>>>(
        means, intr, w2c, meta, counts);
    fuse_kernel<<<dim3(2048, 8), dim3(256), 0, stream>>>(
        feats, meta, counts, fusedP);
    conv_kernel<1><<<dim3(1024), dim3(512), 0, stream>>>(
        fusedP, wT, b1, (void*)x1P);
    conv_kernel<2><<<dim3(1024), dim3(512), 0, stream>>>(
        x1P, wT + 36864, b2, d_out);
}